// Round 19
// baseline (938.754 us; speedup 1.0000x reference)
//
#include <hip/hip_runtime.h>

#define MTPB 1024    // MLP kernel: 16 waves
#define BM 64
#define SCHUNK 8192  // edges per (chunk, range) block in partitioned scatter

typedef float f32x4 __attribute__((ext_vector_type(4)));
typedef short s16x8 __attribute__((ext_vector_type(8)));

// ===========================================================================
// bf16 helpers. prep_w uses round-to-nearest (one-time); the MLP hot path
// uses TRUNCATION split (hi=trunc(f), lo=trunc(f-hi), err <= 2^-16 rel).
// ===========================================================================
__device__ __forceinline__ unsigned short f2bh(float f)
{
    unsigned u = __float_as_uint(f);
    unsigned r = u + 0x7fffu + ((u >> 16) & 1u);
    return (unsigned short)(r >> 16);
}
__device__ __forceinline__ float bh2f(unsigned short h)
{
    return __uint_as_float((unsigned)h << 16);
}

// ---------------------------------------------------------------------------
// Fragment-ordered act LDS layout (ushort units, row stride 128):
// row r's k-chunk ks (32 elems) -> 4 16B slots, slot g = MFMA A-fragment of
// lane-group g (k = ks*32 + 4g + {0..3,16..19}); slot XOR-swizzled with r&7.
// ---------------------------------------------------------------------------
__device__ __forceinline__ int fpos(int r, int k)
{
    int ks = k >> 5, p = k & 31;
    int g = (p & 15) >> 2;
    int i = (p & 3) + ((p >> 4) << 2);
    int slot = (ks * 4 + g) ^ (r & 7);
    return r * 128 + slot * 8 + i;
}

// ===========================================================================
// CSR build. count: FLAT single pass (atomics never had scatter's
// line-allocation pathology; partitioned count cost 7x dst re-reads).
// scatter: XCD-range-partitioned (r16: 390us -> off the profile).
// ===========================================================================
__global__ void count_kernel(const int* __restrict__ ei, int* __restrict__ cnt, int E)
{
    int e = blockIdx.x * blockDim.x + threadIdx.x;
    if (e >= E) return;
    atomicAdd(cnt + ei[E + e], 1);
}

__global__ void scan_blocks(const int* __restrict__ cnt, int* __restrict__ rs,
                            int* __restrict__ part, int N)
{
    __shared__ int sums[256];
    int t = threadIdx.x;
    int base = blockIdx.x * 2048 + t * 8;
    int v[8], s = 0;
#pragma unroll
    for (int i = 0; i < 8; i++) { int idx = base + i; v[i] = (idx < N) ? cnt[idx] : 0; s += v[i]; }
    sums[t] = s;
    __syncthreads();
    for (int off = 1; off < 256; off <<= 1) {
        int x = (t >= off) ? sums[t - off] : 0;
        __syncthreads();
        if (t >= off) sums[t] += x;
        __syncthreads();
    }
    int run = (t == 0) ? 0 : sums[t - 1];
#pragma unroll
    for (int i = 0; i < 8; i++) { int idx = base + i; if (idx < N) rs[idx] = run; run += v[i]; }
    if (t == 255) part[blockIdx.x] = sums[255];
}

__global__ void scan_part(int* __restrict__ part, int nb)
{
    __shared__ int sums[256];
    int t = threadIdx.x;
    int base = t * 8;
    int v[8], s = 0;
#pragma unroll
    for (int i = 0; i < 8; i++) { int idx = base + i; v[i] = (idx < nb) ? part[idx] : 0; s += v[i]; }
    sums[t] = s;
    __syncthreads();
    for (int off = 1; off < 256; off <<= 1) {
        int x = (t >= off) ? sums[t - off] : 0;
        __syncthreads();
        if (t >= off) sums[t] += x;
        __syncthreads();
    }
    int run = (t == 0) ? 0 : sums[t - 1];
#pragma unroll
    for (int i = 0; i < 8; i++) { int idx = base + i; if (idx < nb) part[idx] = run; run += v[i]; }
}

__global__ void scan_fixup(int* __restrict__ rs, int* __restrict__ cursor,
                           const int* __restrict__ part, int N, int E)
{
    int i = blockIdx.x * blockDim.x + threadIdx.x;
    if (i < N) { int v = rs[i] + part[i >> 11]; rs[i] = v; cursor[i] = v; }
    if (i == 0) rs[N] = E;
}

__global__ void scatter_kernel(const int* __restrict__ ei, int* __restrict__ cursor,
                               int* __restrict__ col, int E, int N8)
{
    int r = blockIdx.x & 7;
    int chunk = blockIdx.x >> 3;
    int lo = r * N8, hi = lo + N8;
    int e0 = chunk * SCHUNK;
    int e1 = e0 + SCHUNK; if (e1 > E) e1 = E;
    for (int e = e0 + threadIdx.x; e < e1; e += blockDim.x) {
        int d = ei[E + e];
        if (d >= lo && d < hi) {
            int p = atomicAdd(cursor + d, 1);
            col[p] = ei[e];
        }
    }
}

// ===========================================================================
// Standalone CSR gathers (separate kernels so their register pressure never
// touches the MLP kernel — r9/r11 lesson). Latency-bound, no launch bounds.
// ===========================================================================
__global__ void gather_cla_kernel(const int* __restrict__ rs, const int* __restrict__ col,
                                  const float* __restrict__ state,
                                  float* __restrict__ agg, float* __restrict__ deg,
                                  int nvar2, int n)
{
    int gwave = (blockIdx.x * blockDim.x + threadIdx.x) >> 6;
    int lane = threadIdx.x & 63;
    for (int i = 0; i < 8; i++) {
        int node = gwave * 8 + i;
        if (node >= n) return;
        int d0 = rs[node], d1 = rs[node + 1];
        float acc = 0.0f;
        int e = d0;
        for (; e + 4 <= d1; e += 4) {
            int s0 = col[e], s1 = col[e + 1], s2 = col[e + 2], s3 = col[e + 3];
            float a0 = (s0 < nvar2) ? state[(long)s0 * 64 + lane] : 0.0f;
            float a1 = (s1 < nvar2) ? state[(long)s1 * 64 + lane] : 0.0f;
            float a2 = (s2 < nvar2) ? state[(long)s2 * 64 + lane] : 0.0f;
            float a3 = (s3 < nvar2) ? state[(long)s3 * 64 + lane] : 0.0f;
            acc += a0 + a1 + a2 + a3;
        }
        for (; e < d1; e++) {
            int s = col[e];
            if (s < nvar2) acc += state[(long)s * 64 + lane];
        }
        agg[(long)node * 64 + lane] = acc;
        if (lane == 0) deg[node] = (float)(d1 - d0);
    }
}

__global__ void gather_var_kernel(const int* __restrict__ rs, const int* __restrict__ col,
                                  const float* __restrict__ posr,
                                  float* __restrict__ agg, float* __restrict__ deg,
                                  int nvar, int n2)
{
    int gwave = (blockIdx.x * blockDim.x + threadIdx.x) >> 6;
    int lane = threadIdx.x & 63;
    int f = lane & 15, sub = lane >> 4;
    int nvar2 = 2 * nvar;
    for (int i = 0; i < 2; i++) {
        int node = gwave * 8 + i * 4 + sub;
        if (node < n2) {
            int d0 = rs[node], d1 = rs[node + 1];
            float acc = 0.0f;
            int e = d0;
            for (; e + 2 <= d1; e += 2) {
                int s0 = col[e], s1 = col[e + 1];
                float a0 = 0.0f, a1 = 0.0f;
                if (s0 < nvar2) {
                    a0 = posr[(long)((s0 < nvar) ? s0 : s0 - nvar) * 16 + f];
                    if (s0 >= nvar) a0 = -a0;
                }
                if (s1 < nvar2) {
                    a1 = posr[(long)((s1 < nvar) ? s1 : s1 - nvar) * 16 + f];
                    if (s1 >= nvar) a1 = -a1;
                }
                acc += a0 + a1;
            }
            for (; e < d1; e++) {
                int s = col[e];
                if (s < nvar2) {
                    float a = posr[(long)((s < nvar) ? s : s - nvar) * 16 + f];
                    acc += (s < nvar) ? a : -a;
                }
            }
            agg[(long)node * 16 + f] = acc;
            if (f == 0) deg[node] = (float)(d1 - d0);
        }
    }
}

// ===========================================================================
// Weight prep: fp32 W[K][C] -> fragment-ordered bf16 hi/lo for
// mfma_f32_16x16x32_bf16 B-operand (lane l, col-tile ct, k-step ks:
// col = ct*16+(l&15), k = ks*32+4*(l>>4)+(i&3)+16*(i>>2)).
// ===========================================================================
__global__ void prep_w(const float* __restrict__ W, int K_real, int C, int NKS,
                       unsigned short* __restrict__ dhi, unsigned short* __restrict__ dlo)
{
    int t = blockIdx.x * blockDim.x + threadIdx.x;
    int total = (C / 16) * NKS * 64;
    if (t >= total) return;
    int l = t & 63;
    int rest = t >> 6;
    int ks = rest % NKS;
    int ct = rest / NKS;
    int colg = ct * 16 + (l & 15);
#pragma unroll
    for (int i = 0; i < 8; i++) {
        int k = ks * 32 + 4 * (l >> 4) + (i & 3) + 16 * (i >> 2);
        float v = (k < K_real) ? W[(long)k * C + colg] : 0.0f;
        unsigned short h = f2bh(v);
        dhi[(long)t * 8 + i] = h;
        dlo[(long)t * 8 + i] = f2bh(v - bh2f(h));
    }
}

// ===========================================================================
// Split-bf16 MFMA GEMM layer, ping-pong, tile-sequential (32-VGPR
// discipline), fragment-ordered act (1 ds_read_b128 per A-fragment).
// 3 MFMA per (ks,tile): hi*hi + hi*lo + lo*hi. One barrier per layer.
// F32O: write raw fp32 to (float*)oh (for the layer feeding pW3 only).
// ===========================================================================
template<int NKS, int NT, bool RELU, bool L0S, bool F32O>
__device__ __forceinline__ void mfma_gemm(
    const unsigned short* __restrict__ ih, const unsigned short* __restrict__ il,
    unsigned short* __restrict__ oh, unsigned short* __restrict__ ol,
    const unsigned short* __restrict__ wh, const unsigned short* __restrict__ wl,
    const float* __restrict__ bias, const float* __restrict__ ldeg,
    float* __restrict__ state_g, long base, int n)
{
    const int tid = threadIdx.x;
    const int w = tid >> 6, l = tid & 63;
    const int rs_ = w & 3;            // row stripe (16 rows)
    const int cq = w >> 2;            // col quarter
    const int ar = rs_ * 16 + (l & 15);
    const int abase = ar * 128;       // row base (ushorts)
    const int ax = (ar & 7) << 3;     // swizzle XOR (ushort offset)
    const int g8 = (l >> 4) << 3;     // lane-group slot offset (ushorts)
    const int orow = rs_ * 16 + (l >> 4) * 4;

#pragma unroll 1
    for (int t = 0; t < NT; ++t) {
        f32x4 acc = {0.f, 0.f, 0.f, 0.f};
        const int ct = cq * NT + t;
#pragma unroll 1
        for (int ks = 0; ks < NKS; ++ks) {
            int ao = abase + ((ks * 32 + g8) ^ ax);
            union { uint4 u; s16x8 s; } fah, fal, fbh, fbl;
            fah.u = *(const uint4*)(ih + ao);
            fal.u = *(const uint4*)(il + ao);
            long off = (long)((ct * NKS + ks) * 64 + l) * 8;
            fbh.u = *(const uint4*)(wh + off);
            fbl.u = *(const uint4*)(wl + off);
            acc = __builtin_amdgcn_mfma_f32_16x16x32_bf16(fah.s, fbh.s, acc, 0, 0, 0);
            acc = __builtin_amdgcn_mfma_f32_16x16x32_bf16(fah.s, fbl.s, acc, 0, 0, 0);
            acc = __builtin_amdgcn_mfma_f32_16x16x32_bf16(fal.s, fbh.s, acc, 0, 0, 0);
        }
        // immediate per-tile epilogue (OUT != IN -> no barrier needed here)
        int colg = ct * 16 + (l & 15);
        int ks2 = colg >> 5, p = colg & 31;
        int slot8 = ((ks2 * 4 + ((p & 15) >> 2)) << 3);
        int i2 = (p & 3) + ((p >> 4) << 2);
        float bv = bias[colg];
#pragma unroll
        for (int i = 0; i < 4; i++) {
            int row = orow + i;
            float sc = L0S ? ldeg[row] : 1.0f;
            float o = acc[i] + sc * bv;
            if (RELU) o = fmaxf(o, 0.0f);
            if (F32O) {
                ((float*)oh)[row * 128 + colg] = o;
            } else {
                unsigned u = __float_as_uint(o);
                float lo = o - __uint_as_float(u & 0xffff0000u);
                int idx = row * 128 + (slot8 ^ ((row & 7) << 3)) + i2;
                oh[idx] = (unsigned short)(u >> 16);
                ol[idx] = (unsigned short)(__float_as_uint(lo) >> 16);
            }
            if (state_g != nullptr && base + row < n)
                state_g[(base + row) * 64 + colg] = o;
        }
    }
    __syncthreads();   // OUT visible to next layer
}

// ===========================================================================
// MLP kernel: stage agg -> buf0, x -> buf1 cols 64..95 (fragment order);
// 6 ping-pong MFMA layers (one barrier each); p2 emits fp32; pW3 runs on
// all 1024 threads (8/output + shuffle reduce). LDS = one 64KB array.
// launch_bounds(1024,8): empirical VGPR cap 32; tile-sequential gemm fits.
// ===========================================================================
template<int K0>
__global__ __launch_bounds__(MTPB, 8)
void mlp_kernel(const float* __restrict__ agg, const float* __restrict__ deg,
                const float* __restrict__ xg,
                const unsigned short* w0h, const unsigned short* w0l,
                const unsigned short* u1h, const unsigned short* u1l,
                const unsigned short* u2h, const unsigned short* u2l,
                const unsigned short* u3h, const unsigned short* u3l,
                const unsigned short* p1h, const unsigned short* p1l,
                const unsigned short* p2h, const unsigned short* p2l,
                const float* __restrict__ b0, const float* __restrict__ ub1,
                const float* __restrict__ ub2, const float* __restrict__ ub3,
                const float* __restrict__ pb1, const float* __restrict__ pb2,
                const float* __restrict__ pW3, const float* __restrict__ pb3,
                float* __restrict__ state_g, float* __restrict__ outg, int n)
{
    __shared__ unsigned short bufs[4 * 64 * 128];
    __shared__ float ldeg[BM];
    unsigned short* a0h = bufs;
    unsigned short* a0l = bufs + 8192;
    unsigned short* a1h = bufs + 16384;
    unsigned short* a1l = bufs + 24576;

    const int tid = threadIdx.x;
    const long base = (long)blockIdx.x * BM;
    constexpr int NKS0 = (K0 == 64) ? 2 : 1;
    constexpr int K0PAD = NKS0 * 32;

    // ---- stage: buf0 cols [0,K0PAD) = agg(+zeros); buf1 cols [64,96) = x(+zeros)
    for (int idx = tid; idx < BM * K0PAD; idx += MTPB) {
        int node = idx / K0PAD, c = idx % K0PAD;
        float v = 0.0f;
        if (c < K0 && base + node < n) v = agg[(base + node) * K0 + c];
        unsigned u = __float_as_uint(v);
        float lo = v - __uint_as_float(u & 0xffff0000u);
        int fp = fpos(node, c);
        a0h[fp] = (unsigned short)(u >> 16);
        a0l[fp] = (unsigned short)(__float_as_uint(lo) >> 16);
    }
    for (int idx = tid; idx < BM * 32; idx += MTPB) {
        int node = idx >> 5, j = idx & 31;
        float v = (j < 3 && base + node < n) ? xg[(base + node) * 3 + j] : 0.0f;
        unsigned u = __float_as_uint(v);
        float lo = v - __uint_as_float(u & 0xffff0000u);
        int fp = fpos(node, 64 + j);
        a1h[fp] = (unsigned short)(u >> 16);
        a1l[fp] = (unsigned short)(__float_as_uint(lo) >> 16);
    }
    if (tid < BM) ldeg[tid] = (base + tid < n) ? deg[base + tid] : 0.0f;
    __syncthreads();

    // layer0: K0 -> 64 (deg-scaled bias) : buf0 -> buf1 (x already at 64..95)
    mfma_gemm<NKS0, 1, false, true , false>(a0h, a0l, a1h, a1l, w0h, w0l, b0, ldeg, nullptr, base, n);
    // update MLP: 96(67) -> 128 relu, 128 -> 128 relu, 128 -> 64 (state out)
    mfma_gemm<3, 2, true,  false, false>(a1h, a1l, a0h, a0l, u1h, u1l, ub1, ldeg, nullptr, base, n);
    mfma_gemm<4, 2, true,  false, false>(a0h, a0l, a1h, a1l, u2h, u2l, ub2, ldeg, nullptr, base, n);
    mfma_gemm<4, 1, false, false, false>(a1h, a1l, a0h, a0l, u3h, u3l, ub3, ldeg, state_g, base, n);
    // predictor: 64 -> 128 relu, 128 -> 128 relu (p2 emits raw fp32 for pW3)
    mfma_gemm<2, 2, true,  false, false>(a0h, a0l, a1h, a1l, p1h, p1l, pb1, ldeg, nullptr, base, n);
    mfma_gemm<4, 2, true,  false, true >(a1h, a1l, bufs, nullptr, p2h, p2l, pb2, ldeg, nullptr, base, n);

    // ---- pW3: 128 -> 2; 8 threads per output element, shuffle-reduce
    {
        const float* fb = (const float*)bufs;
        int out = tid >> 3, sub = tid & 7;       // out 0..127
        int r = out >> 1, c = out & 1;
        float acc = 0.0f;
        int k0 = sub * 16;
#pragma unroll
        for (int kk = 0; kk < 16; kk++) {
            int k = k0 + kk;
            acc = fmaf(fb[r * 128 + k], pW3[k * 2 + c], acc);
        }
        acc += __shfl_xor(acc, 1);
        acc += __shfl_xor(acc, 2);
        acc += __shfl_xor(acc, 4);
        if (sub == 0 && base + r < n) outg[(base + r) * 2 + c] = acc + pb3[c];
    }
}

// ===========================================================================
extern "C" void kernel_launch(void* const* d_in, const int* in_sizes, int n_in,
                              void* d_out, int out_size, void* d_ws, size_t ws_size,
                              hipStream_t stream)
{
    const float* x    = (const float*)d_in[0];
    const int*   ei   = (const int*)d_in[1];
    // d_in[2] = gate_type: fixed ordering [VAR*nvar, NEGVAR*nvar, CLAUSE*ncla]
    const float* posr = (const float*)d_in[3];
    const float* Wr   = (const float*)d_in[4];
    const float* br   = (const float*)d_in[5];
    const float* Wc   = (const float*)d_in[6];
    const float* bc   = (const float*)d_in[7];
    const float* uW1  = (const float*)d_in[8];
    const float* ub1  = (const float*)d_in[9];
    const float* uW2  = (const float*)d_in[10];
    const float* ub2  = (const float*)d_in[11];
    const float* uW3  = (const float*)d_in[12];
    const float* ub3  = (const float*)d_in[13];
    const float* pW1  = (const float*)d_in[14];
    const float* pb1  = (const float*)d_in[15];
    const float* pW2  = (const float*)d_in[16];
    const float* pb2  = (const float*)d_in[17];
    const float* pW3  = (const float*)d_in[18];
    const float* pb3  = (const float*)d_in[19];

    const int N     = in_sizes[0] / 3;
    const int E     = in_sizes[1] / 2;
    const int nvar  = in_sizes[3] / 16;
    const int nvar2 = 2 * nvar;
    const int ncla  = N - nvar2;
    const int N8    = (N + 7) / 8;

    // workspace carve-out
    int* cnt    = (int*)d_ws;              // [N]
    int* rs     = cnt + N;                 // [N+1]
    int* cursor = rs + N + 1;              // [N]
    int* part   = cursor + N;              // [2048]
    int* col    = part + 2048;             // [E]
    size_t foff = ((size_t)(col + E - (int*)d_ws) + 3) & ~(size_t)3;
    float* state = (float*)d_ws + foff;    // [2nvar*64]
    float* agg_v = state + (size_t)nvar2 * 64;   // [2nvar*16]
    float* deg_v = agg_v + (size_t)nvar2 * 16;   // [2nvar]
    float* agg_c = deg_v + nvar2;                // [ncla*64]
    float* deg_c = agg_c + (size_t)ncla * 64;    // [ncla]
    uintptr_t wp = ((uintptr_t)(deg_c + ncla) + 15) & ~(uintptr_t)15;
    unsigned short* H = (unsigned short*)wp;     // fragment-ordered bf16 hi
    const int TH = 67584;                        // total ushorts of all layers
    unsigned short* L = H + TH;                  // bf16 lo
    // per-layer offsets (C*Kpad ushorts each)
    const int oW0v = 0, oW0c = 2048, oU1 = 6144, oU2 = 18432,
              oU3 = 34816, oP1 = 43008, oP2 = 51200;

    // ---- weight prep (tiny, once per call)
    prep_w<<<1, 256, 0, stream>>>(Wr, 16, 64, 1, H + oW0v, L + oW0v);
    prep_w<<<2, 256, 0, stream>>>(Wc, 64, 64, 2, H + oW0c, L + oW0c);
    prep_w<<<6, 256, 0, stream>>>(uW1, 67, 128, 3, H + oU1, L + oU1);
    prep_w<<<8, 256, 0, stream>>>(uW2, 128, 128, 4, H + oU2, L + oU2);
    prep_w<<<4, 256, 0, stream>>>(uW3, 128, 64, 4, H + oU3, L + oU3);
    prep_w<<<4, 256, 0, stream>>>(pW1, 64, 128, 2, H + oP1, L + oP1);
    prep_w<<<8, 256, 0, stream>>>(pW2, 128, 128, 4, H + oP2, L + oP2);

    hipMemsetAsync(cnt, 0, (size_t)N * sizeof(int), stream);

    const int nb = (N + 2047) / 2048;
    const int nchunk = (E + SCHUNK - 1) / SCHUNK;
    count_kernel<<<(E + 255) / 256, 256, 0, stream>>>(ei, cnt, E);
    scan_blocks<<<nb, 256, 0, stream>>>(cnt, rs, part, N);
    scan_part<<<1, 256, 0, stream>>>(part, nb);
    scan_fixup<<<(N + 255) / 256, 256, 0, stream>>>(rs, cursor, part, N, E);
    scatter_kernel<<<nchunk * 8, 256, 0, stream>>>(ei, cursor, col, E, N8);

    {   // var/negvar gather (CSR -> agg_v, deg_v)
        int blocks = (nvar2 + 31) / 32;
        gather_var_kernel<<<blocks, 256, 0, stream>>>(rs, col, posr,
                                                      agg_v, deg_v, nvar, nvar2);
    }
    {   // var/negvar MLP (writes state + out)
        int blocks = (nvar2 + BM - 1) / BM;
        mlp_kernel<16><<<blocks, MTPB, 0, stream>>>(
            agg_v, deg_v, x,
            H + oW0v, L + oW0v, H + oU1, L + oU1, H + oU2, L + oU2,
            H + oU3, L + oU3, H + oP1, L + oP1, H + oP2, L + oP2,
            br, ub1, ub2, ub3, pb1, pb2, pW3, pb3,
            state, (float*)d_out, nvar2);
    }
    {   // clause gather (CSR rows offset by 2nvar -> agg_c, deg_c)
        int blocks = (ncla + 31) / 32;
        gather_cla_kernel<<<blocks, 256, 0, stream>>>(rs + nvar2, col, state,
                                                      agg_c, deg_c, nvar2, ncla);
    }
    {   // clause MLP
        int blocks = (ncla + BM - 1) / BM;
        mlp_kernel<64><<<blocks, MTPB, 0, stream>>>(
            agg_c, deg_c, x + (size_t)nvar2 * 3,
            H + oW0c, L + oW0c, H + oU1, L + oU1, H + oU2, L + oU2,
            H + oU3, L + oU3, H + oP1, L + oP1, H + oP2, L + oP2,
            bc, ub1, ub2, ub3, pb1, pb2, pW3, pb3,
            nullptr, (float*)d_out + (size_t)nvar2 * 2, ncla);
    }
}

// Round 20
// 870.392 us; speedup vs baseline: 1.0785x; 1.0785x over previous
//
#include <hip/hip_runtime.h>

#define MTPB 1024    // MLP kernel: 16 waves
#define BM 64
#define SCHUNK 8192  // edges per (chunk, range) block in partitioned scatter

typedef float f32x4 __attribute__((ext_vector_type(4)));
typedef short s16x8 __attribute__((ext_vector_type(8)));

// ===========================================================================
// bf16 helpers. prep_w uses round-to-nearest (one-time); the MLP hot path
// uses TRUNCATION split (hi=trunc(f), lo=trunc(f-hi), err <= 2^-16 rel).
// ===========================================================================
__device__ __forceinline__ unsigned short f2bh(float f)
{
    unsigned u = __float_as_uint(f);
    unsigned r = u + 0x7fffu + ((u >> 16) & 1u);
    return (unsigned short)(r >> 16);
}
__device__ __forceinline__ float bh2f(unsigned short h)
{
    return __uint_as_float((unsigned)h << 16);
}

// ---------------------------------------------------------------------------
// Fragment-ordered act LDS layout (ushort units, row stride 128):
// row r's k-chunk ks (32 elems) -> 4 16B slots, slot g = MFMA A-fragment of
// lane-group g (k = ks*32 + 4g + {0..3,16..19}); slot XOR-swizzled with r&7.
// ---------------------------------------------------------------------------
__device__ __forceinline__ int fpos(int r, int k)
{
    int ks = k >> 5, p = k & 31;
    int g = (p & 15) >> 2;
    int i = (p & 3) + ((p >> 4) << 2);
    int slot = (ks * 4 + g) ^ (r & 7);
    return r * 128 + slot * 8 + i;
}

// ===========================================================================
// CSR build. count: FLAT single pass (r19 A/B: ~15us cheaper than the
// 8-pass partitioned version; atomics don't have scatter's line-allocation
// pathology). scatter: XCD-range-partitioned (r16: 390us -> off profile).
// ===========================================================================
__global__ void count_kernel(const int* __restrict__ ei, int* __restrict__ cnt, int E)
{
    int e = blockIdx.x * blockDim.x + threadIdx.x;
    if (e >= E) return;
    atomicAdd(cnt + ei[E + e], 1);
}

__global__ void scan_blocks(const int* __restrict__ cnt, int* __restrict__ rs,
                            int* __restrict__ part, int N)
{
    __shared__ int sums[256];
    int t = threadIdx.x;
    int base = blockIdx.x * 2048 + t * 8;
    int v[8], s = 0;
#pragma unroll
    for (int i = 0; i < 8; i++) { int idx = base + i; v[i] = (idx < N) ? cnt[idx] : 0; s += v[i]; }
    sums[t] = s;
    __syncthreads();
    for (int off = 1; off < 256; off <<= 1) {
        int x = (t >= off) ? sums[t - off] : 0;
        __syncthreads();
        if (t >= off) sums[t] += x;
        __syncthreads();
    }
    int run = (t == 0) ? 0 : sums[t - 1];
#pragma unroll
    for (int i = 0; i < 8; i++) { int idx = base + i; if (idx < N) rs[idx] = run; run += v[i]; }
    if (t == 255) part[blockIdx.x] = sums[255];
}

__global__ void scan_part(int* __restrict__ part, int nb)
{
    __shared__ int sums[256];
    int t = threadIdx.x;
    int base = t * 8;
    int v[8], s = 0;
#pragma unroll
    for (int i = 0; i < 8; i++) { int idx = base + i; v[i] = (idx < nb) ? part[idx] : 0; s += v[i]; }
    sums[t] = s;
    __syncthreads();
    for (int off = 1; off < 256; off <<= 1) {
        int x = (t >= off) ? sums[t - off] : 0;
        __syncthreads();
        if (t >= off) sums[t] += x;
        __syncthreads();
    }
    int run = (t == 0) ? 0 : sums[t - 1];
#pragma unroll
    for (int i = 0; i < 8; i++) { int idx = base + i; if (idx < nb) part[idx] = run; run += v[i]; }
}

__global__ void scan_fixup(int* __restrict__ rs, int* __restrict__ cursor,
                           const int* __restrict__ part, int N, int E)
{
    int i = blockIdx.x * blockDim.x + threadIdx.x;
    if (i < N) { int v = rs[i] + part[i >> 11]; rs[i] = v; cursor[i] = v; }
    if (i == 0) rs[N] = E;
}

__global__ void scatter_kernel(const int* __restrict__ ei, int* __restrict__ cursor,
                               int* __restrict__ col, int E, int N8)
{
    int r = blockIdx.x & 7;
    int chunk = blockIdx.x >> 3;
    int lo = r * N8, hi = lo + N8;
    int e0 = chunk * SCHUNK;
    int e1 = e0 + SCHUNK; if (e1 > E) e1 = E;
    for (int e = e0 + threadIdx.x; e < e1; e += blockDim.x) {
        int d = ei[E + e];
        if (d >= lo && d < hi) {
            int p = atomicAdd(cursor + d, 1);
            col[p] = ei[e];
        }
    }
}

// ===========================================================================
// Standalone CSR gathers (separate kernels so their register pressure never
// touches the MLP kernel — r9/r11 lesson). Latency-bound, no launch bounds.
// ===========================================================================
__global__ void gather_cla_kernel(const int* __restrict__ rs, const int* __restrict__ col,
                                  const float* __restrict__ state,
                                  float* __restrict__ agg, float* __restrict__ deg,
                                  int nvar2, int n)
{
    int gwave = (blockIdx.x * blockDim.x + threadIdx.x) >> 6;
    int lane = threadIdx.x & 63;
    for (int i = 0; i < 8; i++) {
        int node = gwave * 8 + i;
        if (node >= n) return;
        int d0 = rs[node], d1 = rs[node + 1];
        float acc = 0.0f;
        int e = d0;
        for (; e + 4 <= d1; e += 4) {
            int s0 = col[e], s1 = col[e + 1], s2 = col[e + 2], s3 = col[e + 3];
            float a0 = (s0 < nvar2) ? state[(long)s0 * 64 + lane] : 0.0f;
            float a1 = (s1 < nvar2) ? state[(long)s1 * 64 + lane] : 0.0f;
            float a2 = (s2 < nvar2) ? state[(long)s2 * 64 + lane] : 0.0f;
            float a3 = (s3 < nvar2) ? state[(long)s3 * 64 + lane] : 0.0f;
            acc += a0 + a1 + a2 + a3;
        }
        for (; e < d1; e++) {
            int s = col[e];
            if (s < nvar2) acc += state[(long)s * 64 + lane];
        }
        agg[(long)node * 64 + lane] = acc;
        if (lane == 0) deg[node] = (float)(d1 - d0);
    }
}

__global__ void gather_var_kernel(const int* __restrict__ rs, const int* __restrict__ col,
                                  const float* __restrict__ posr,
                                  float* __restrict__ agg, float* __restrict__ deg,
                                  int nvar, int n2)
{
    int gwave = (blockIdx.x * blockDim.x + threadIdx.x) >> 6;
    int lane = threadIdx.x & 63;
    int f = lane & 15, sub = lane >> 4;
    int nvar2 = 2 * nvar;
    for (int i = 0; i < 2; i++) {
        int node = gwave * 8 + i * 4 + sub;
        if (node < n2) {
            int d0 = rs[node], d1 = rs[node + 1];
            float acc = 0.0f;
            int e = d0;
            for (; e + 2 <= d1; e += 2) {
                int s0 = col[e], s1 = col[e + 1];
                float a0 = 0.0f, a1 = 0.0f;
                if (s0 < nvar2) {
                    a0 = posr[(long)((s0 < nvar) ? s0 : s0 - nvar) * 16 + f];
                    if (s0 >= nvar) a0 = -a0;
                }
                if (s1 < nvar2) {
                    a1 = posr[(long)((s1 < nvar) ? s1 : s1 - nvar) * 16 + f];
                    if (s1 >= nvar) a1 = -a1;
                }
                acc += a0 + a1;
            }
            for (; e < d1; e++) {
                int s = col[e];
                if (s < nvar2) {
                    float a = posr[(long)((s < nvar) ? s : s - nvar) * 16 + f];
                    acc += (s < nvar) ? a : -a;
                }
            }
            agg[(long)node * 16 + f] = acc;
            if (f == 0) deg[node] = (float)(d1 - d0);
        }
    }
}

// ===========================================================================
// Weight prep: fp32 W[K][C] -> fragment-ordered bf16 hi/lo for
// mfma_f32_16x16x32_bf16 B-operand (lane l, col-tile ct, k-step ks:
// col = ct*16+(l&15), k = ks*32+4*(l>>4)+(i&3)+16*(i>>2)).
// ===========================================================================
__global__ void prep_w(const float* __restrict__ W, int K_real, int C, int NKS,
                       unsigned short* __restrict__ dhi, unsigned short* __restrict__ dlo)
{
    int t = blockIdx.x * blockDim.x + threadIdx.x;
    int total = (C / 16) * NKS * 64;
    if (t >= total) return;
    int l = t & 63;
    int rest = t >> 6;
    int ks = rest % NKS;
    int ct = rest / NKS;
    int colg = ct * 16 + (l & 15);
#pragma unroll
    for (int i = 0; i < 8; i++) {
        int k = ks * 32 + 4 * (l >> 4) + (i & 3) + 16 * (i >> 2);
        float v = (k < K_real) ? W[(long)k * C + colg] : 0.0f;
        unsigned short h = f2bh(v);
        dhi[(long)t * 8 + i] = h;
        dlo[(long)t * 8 + i] = f2bh(v - bh2f(h));
    }
}

// ===========================================================================
// Split-bf16 MFMA GEMM layer, ping-pong, tile-sequential (32-VGPR
// discipline), fragment-ordered act (1 ds_read_b128 per A-fragment).
// 3 MFMA per (ks,tile): hi*hi + hi*lo + lo*hi. One barrier per layer.
// (r19's f32-epilogue variant regressed: row-major f32 stores are a 4-way
// bank conflict; the swizzled hi/lo epilogue stays.)
// ===========================================================================
template<int NKS, int NT, bool RELU, bool L0S>
__device__ __forceinline__ void mfma_gemm(
    const unsigned short* __restrict__ ih, const unsigned short* __restrict__ il,
    unsigned short* __restrict__ oh, unsigned short* __restrict__ ol,
    const unsigned short* __restrict__ wh, const unsigned short* __restrict__ wl,
    const float* __restrict__ bias, const float* __restrict__ ldeg,
    float* __restrict__ state_g, long base, int n)
{
    const int tid = threadIdx.x;
    const int w = tid >> 6, l = tid & 63;
    const int rs_ = w & 3;            // row stripe (16 rows)
    const int cq = w >> 2;            // col quarter
    const int ar = rs_ * 16 + (l & 15);
    const int abase = ar * 128;       // row base (ushorts)
    const int ax = (ar & 7) << 3;     // swizzle XOR (ushort offset)
    const int g8 = (l >> 4) << 3;     // lane-group slot offset (ushorts)
    const int orow = rs_ * 16 + (l >> 4) * 4;

#pragma unroll 1
    for (int t = 0; t < NT; ++t) {
        f32x4 acc = {0.f, 0.f, 0.f, 0.f};
        const int ct = cq * NT + t;
#pragma unroll 1
        for (int ks = 0; ks < NKS; ++ks) {
            int ao = abase + ((ks * 32 + g8) ^ ax);
            union { uint4 u; s16x8 s; } fah, fal, fbh, fbl;
            fah.u = *(const uint4*)(ih + ao);
            fal.u = *(const uint4*)(il + ao);
            long off = (long)((ct * NKS + ks) * 64 + l) * 8;
            fbh.u = *(const uint4*)(wh + off);
            fbl.u = *(const uint4*)(wl + off);
            acc = __builtin_amdgcn_mfma_f32_16x16x32_bf16(fah.s, fbh.s, acc, 0, 0, 0);
            acc = __builtin_amdgcn_mfma_f32_16x16x32_bf16(fah.s, fbl.s, acc, 0, 0, 0);
            acc = __builtin_amdgcn_mfma_f32_16x16x32_bf16(fal.s, fbh.s, acc, 0, 0, 0);
        }
        // immediate per-tile epilogue (OUT != IN -> no barrier needed here)
        int colg = ct * 16 + (l & 15);
        int ks2 = colg >> 5, p = colg & 31;
        int slot8 = ((ks2 * 4 + ((p & 15) >> 2)) << 3);
        int i2 = (p & 3) + ((p >> 4) << 2);
        float bv = bias[colg];
#pragma unroll
        for (int i = 0; i < 4; i++) {
            int row = orow + i;
            float sc = L0S ? ldeg[row] : 1.0f;
            float o = acc[i] + sc * bv;
            if (RELU) o = fmaxf(o, 0.0f);
            unsigned u = __float_as_uint(o);
            float lo = o - __uint_as_float(u & 0xffff0000u);
            int idx = row * 128 + (slot8 ^ ((row & 7) << 3)) + i2;
            oh[idx] = (unsigned short)(u >> 16);
            ol[idx] = (unsigned short)(__float_as_uint(lo) >> 16);
            if (state_g != nullptr && base + row < n)
                state_g[(base + row) * 64 + colg] = o;
        }
    }
    __syncthreads();   // OUT visible to next layer
}

// ===========================================================================
// MLP kernel (r18 structure — best measured): stage agg -> buf0, x -> buf1
// cols 64..95 (fragment order); 6 ping-pong MFMA layers (one barrier each)
// + serial-128-thread pW3. LDS = 4x16KB + ldeg.
// launch_bounds(1024,8): empirical VGPR cap 32; tile-sequential gemm fits.
// ===========================================================================
template<int K0>
__global__ __launch_bounds__(MTPB, 8)
void mlp_kernel(const float* __restrict__ agg, const float* __restrict__ deg,
                const float* __restrict__ xg,
                const unsigned short* w0h, const unsigned short* w0l,
                const unsigned short* u1h, const unsigned short* u1l,
                const unsigned short* u2h, const unsigned short* u2l,
                const unsigned short* u3h, const unsigned short* u3l,
                const unsigned short* p1h, const unsigned short* p1l,
                const unsigned short* p2h, const unsigned short* p2l,
                const float* __restrict__ b0, const float* __restrict__ ub1,
                const float* __restrict__ ub2, const float* __restrict__ ub3,
                const float* __restrict__ pb1, const float* __restrict__ pb2,
                const float* __restrict__ pW3, const float* __restrict__ pb3,
                float* __restrict__ state_g, float* __restrict__ outg, int n)
{
    __shared__ unsigned short a0h[64 * 128];
    __shared__ unsigned short a0l[64 * 128];
    __shared__ unsigned short a1h[64 * 128];
    __shared__ unsigned short a1l[64 * 128];
    __shared__ float ldeg[BM];

    const int tid = threadIdx.x;
    const long base = (long)blockIdx.x * BM;
    constexpr int NKS0 = (K0 == 64) ? 2 : 1;
    constexpr int K0PAD = NKS0 * 32;

    // ---- stage: buf0 cols [0,K0PAD) = agg(+zeros); buf1 cols [64,96) = x(+zeros)
    for (int idx = tid; idx < BM * K0PAD; idx += MTPB) {
        int node = idx / K0PAD, c = idx % K0PAD;
        float v = 0.0f;
        if (c < K0 && base + node < n) v = agg[(base + node) * K0 + c];
        unsigned u = __float_as_uint(v);
        float lo = v - __uint_as_float(u & 0xffff0000u);
        int fp = fpos(node, c);
        a0h[fp] = (unsigned short)(u >> 16);
        a0l[fp] = (unsigned short)(__float_as_uint(lo) >> 16);
    }
    for (int idx = tid; idx < BM * 32; idx += MTPB) {
        int node = idx >> 5, j = idx & 31;
        float v = (j < 3 && base + node < n) ? xg[(base + node) * 3 + j] : 0.0f;
        unsigned u = __float_as_uint(v);
        float lo = v - __uint_as_float(u & 0xffff0000u);
        int fp = fpos(node, 64 + j);
        a1h[fp] = (unsigned short)(u >> 16);
        a1l[fp] = (unsigned short)(__float_as_uint(lo) >> 16);
    }
    if (tid < BM) ldeg[tid] = (base + tid < n) ? deg[base + tid] : 0.0f;
    __syncthreads();

    // layer0: K0 -> 64 (deg-scaled bias) : buf0 -> buf1 (x already at 64..95)
    mfma_gemm<NKS0, 1, false, true >(a0h, a0l, a1h, a1l, w0h, w0l, b0, ldeg, nullptr, base, n);
    // update MLP: 96(67) -> 128 relu, 128 -> 128 relu, 128 -> 64 (state out)
    mfma_gemm<3, 2, true,  false>(a1h, a1l, a0h, a0l, u1h, u1l, ub1, ldeg, nullptr, base, n);
    mfma_gemm<4, 2, true,  false>(a0h, a0l, a1h, a1l, u2h, u2l, ub2, ldeg, nullptr, base, n);
    mfma_gemm<4, 1, false, false>(a1h, a1l, a0h, a0l, u3h, u3l, ub3, ldeg, state_g, base, n);
    // predictor: 64 -> 128 relu, 128 -> 128 relu
    mfma_gemm<2, 2, true,  false>(a0h, a0l, a1h, a1l, p1h, p1l, pb1, ldeg, nullptr, base, n);
    mfma_gemm<4, 2, true,  false>(a1h, a1l, a0h, a0l, p2h, p2l, pb2, ldeg, nullptr, base, n);

    // ---- pW3: 128 -> 2 on VALU (reconstruct fp32 act = hi + lo) from buf0
    if (tid < 128) {
        int r = tid >> 1, c = tid & 1;
        float acc = pb3[c];
        for (int k = 0; k < 128; k++) {
            int fp = fpos(r, k);
            float f = bh2f(a0h[fp]) + bh2f(a0l[fp]);
            acc = fmaf(f, pW3[k * 2 + c], acc);
        }
        if (base + r < n) outg[(base + r) * 2 + c] = acc;
    }
}

// ===========================================================================
extern "C" void kernel_launch(void* const* d_in, const int* in_sizes, int n_in,
                              void* d_out, int out_size, void* d_ws, size_t ws_size,
                              hipStream_t stream)
{
    const float* x    = (const float*)d_in[0];
    const int*   ei   = (const int*)d_in[1];
    // d_in[2] = gate_type: fixed ordering [VAR*nvar, NEGVAR*nvar, CLAUSE*ncla]
    const float* posr = (const float*)d_in[3];
    const float* Wr   = (const float*)d_in[4];
    const float* br   = (const float*)d_in[5];
    const float* Wc   = (const float*)d_in[6];
    const float* bc   = (const float*)d_in[7];
    const float* uW1  = (const float*)d_in[8];
    const float* ub1  = (const float*)d_in[9];
    const float* uW2  = (const float*)d_in[10];
    const float* ub2  = (const float*)d_in[11];
    const float* uW3  = (const float*)d_in[12];
    const float* ub3  = (const float*)d_in[13];
    const float* pW1  = (const float*)d_in[14];
    const float* pb1  = (const float*)d_in[15];
    const float* pW2  = (const float*)d_in[16];
    const float* pb2  = (const float*)d_in[17];
    const float* pW3  = (const float*)d_in[18];
    const float* pb3  = (const float*)d_in[19];

    const int N     = in_sizes[0] / 3;
    const int E     = in_sizes[1] / 2;
    const int nvar  = in_sizes[3] / 16;
    const int nvar2 = 2 * nvar;
    const int ncla  = N - nvar2;
    const int N8    = (N + 7) / 8;

    // workspace carve-out
    int* cnt    = (int*)d_ws;              // [N]
    int* rs     = cnt + N;                 // [N+1]
    int* cursor = rs + N + 1;              // [N]
    int* part   = cursor + N;              // [2048]
    int* col    = part + 2048;             // [E]
    size_t foff = ((size_t)(col + E - (int*)d_ws) + 3) & ~(size_t)3;
    float* state = (float*)d_ws + foff;    // [2nvar*64]
    float* agg_v = state + (size_t)nvar2 * 64;   // [2nvar*16]
    float* deg_v = agg_v + (size_t)nvar2 * 16;   // [2nvar]
    float* agg_c = deg_v + nvar2;                // [ncla*64]
    float* deg_c = agg_c + (size_t)ncla * 64;    // [ncla]
    uintptr_t wp = ((uintptr_t)(deg_c + ncla) + 15) & ~(uintptr_t)15;
    unsigned short* H = (unsigned short*)wp;     // fragment-ordered bf16 hi
    const int TH = 67584;                        // total ushorts of all layers
    unsigned short* L = H + TH;                  // bf16 lo
    // per-layer offsets (C*Kpad ushorts each)
    const int oW0v = 0, oW0c = 2048, oU1 = 6144, oU2 = 18432,
              oU3 = 34816, oP1 = 43008, oP2 = 51200;

    // ---- weight prep (tiny, once per call)
    prep_w<<<1, 256, 0, stream>>>(Wr, 16, 64, 1, H + oW0v, L + oW0v);
    prep_w<<<2, 256, 0, stream>>>(Wc, 64, 64, 2, H + oW0c, L + oW0c);
    prep_w<<<6, 256, 0, stream>>>(uW1, 67, 128, 3, H + oU1, L + oU1);
    prep_w<<<8, 256, 0, stream>>>(uW2, 128, 128, 4, H + oU2, L + oU2);
    prep_w<<<4, 256, 0, stream>>>(uW3, 128, 64, 4, H + oU3, L + oU3);
    prep_w<<<4, 256, 0, stream>>>(pW1, 64, 128, 2, H + oP1, L + oP1);
    prep_w<<<8, 256, 0, stream>>>(pW2, 128, 128, 4, H + oP2, L + oP2);

    hipMemsetAsync(cnt, 0, (size_t)N * sizeof(int), stream);

    const int nb = (N + 2047) / 2048;
    const int nchunk = (E + SCHUNK - 1) / SCHUNK;
    count_kernel<<<(E + 255) / 256, 256, 0, stream>>>(ei, cnt, E);
    scan_blocks<<<nb, 256, 0, stream>>>(cnt, rs, part, N);
    scan_part<<<1, 256, 0, stream>>>(part, nb);
    scan_fixup<<<(N + 255) / 256, 256, 0, stream>>>(rs, cursor, part, N, E);
    scatter_kernel<<<nchunk * 8, 256, 0, stream>>>(ei, cursor, col, E, N8);

    {   // var/negvar gather (CSR -> agg_v, deg_v)
        int blocks = (nvar2 + 31) / 32;
        gather_var_kernel<<<blocks, 256, 0, stream>>>(rs, col, posr,
                                                      agg_v, deg_v, nvar, nvar2);
    }
    {   // var/negvar MLP (writes state + out)
        int blocks = (nvar2 + BM - 1) / BM;
        mlp_kernel<16><<<blocks, MTPB, 0, stream>>>(
            agg_v, deg_v, x,
            H + oW0v, L + oW0v, H + oU1, L + oU1, H + oU2, L + oU2,
            H + oU3, L + oU3, H + oP1, L + oP1, H + oP2, L + oP2,
            br, ub1, ub2, ub3, pb1, pb2, pW3, pb3,
            state, (float*)d_out, nvar2);
    }
    {   // clause gather (CSR rows offset by 2nvar -> agg_c, deg_c)
        int blocks = (ncla + 31) / 32;
        gather_cla_kernel<<<blocks, 256, 0, stream>>>(rs + nvar2, col, state,
                                                      agg_c, deg_c, nvar2, ncla);
    }
    {   // clause MLP
        int blocks = (ncla + BM - 1) / BM;
        mlp_kernel<64><<<blocks, MTPB, 0, stream>>>(
            agg_c, deg_c, x + (size_t)nvar2 * 3,
            H + oW0c, L + oW0c, H + oU1, L + oU1, H + oU2, L + oU2,
            H + oU3, L + oU3, H + oP1, L + oP1, H + oP2, L + oP2,
            bc, ub1, ub2, ub3, pb1, pb2, pW3, pb3,
            nullptr, (float*)d_out + (size_t)nvar2 * 2, ncla);
    }
}